// Round 12
// baseline (487.151 us; speedup 1.0000x reference)
//
#include <hip/hip_runtime.h>
#include <hip/hip_fp16.h>
#include <math.h>

#define TSTEPS 6
#define NN 20000
#define NE 320000
#define INF 11
#define XPAD 16
#define HID 64
#define OUTF 3
#define NPW 4                     // nodes per wave in fused kernels
#define WPB 8                     // waves per block (512 threads); NN % (WPB*NPW) == 0
#define EPMAX (NE + 7 * NN)       // CSR slots after pad-to-8
#define NB ((NN + 255) / 256)     // scan blocks = 79

__device__ __forceinline__ float bcast(float v, int l) {
    return __uint_as_float(__builtin_amdgcn_readlane(__float_as_uint(v), l));
}

__device__ __forceinline__ float tanh_safe(float a) {
    float e2 = __expf(-2.0f * fabsf(a));
    float t = (1.0f - e2) / (1.0f + e2);
    return copysignf(t, a);
}

// ---------------- setup kernels (once per call) ----------------

__global__ void k_cnt(const int* __restrict__ src, const int* __restrict__ dst,
                      int* __restrict__ degi, int* __restrict__ indeg, int E) {
    int e = blockIdx.x * blockDim.x + threadIdx.x;
    if (e >= E) return;
    atomicAdd(&degi[src[e]], 1);
    atomicAdd(&indeg[dst[e]], 1);
}

__global__ void k_dis(const int* __restrict__ degi, float* __restrict__ dis, int n) {
    int i = blockIdx.x * blockDim.x + threadIdx.x;
    if (i < n) {
        float d = (float)degi[i];
        dis[i] = d > 0.0f ? rsqrtf(fmaxf(d, 1.0f)) : 0.0f;
    }
}

// scanA: per-block inclusive scan of padded indeg into part, block totals to bsum
__global__ __launch_bounds__(256) void k_scanA(const int* __restrict__ indeg,
                                               int* __restrict__ part,
                                               int* __restrict__ bsum, int n) {
    int idx = blockIdx.x * 256 + threadIdx.x;
    int lane = threadIdx.x & 63, wv = threadIdx.x >> 6;
    int v = (idx < n) ? ((indeg[idx] + 7) & ~7) : 0;
#pragma unroll
    for (int off = 1; off < 64; off <<= 1) {
        int t = __shfl_up(v, off);
        if (lane >= off) v += t;
    }
    __shared__ int wsum[4];
    if (lane == 63) wsum[wv] = v;
    __syncthreads();
    int add = 0;
    for (int w = 0; w < wv; ++w) add += wsum[w];
    v += add;
    if (idx < n) part[idx] = v;
    if (threadIdx.x == 255) bsum[blockIdx.x] = v;
}

__global__ __launch_bounds__(128) void k_scanB(const int* __restrict__ bsum,
                                               int* __restrict__ boff, int nb) {
    int tid = threadIdx.x;
    int lane = tid & 63, wv = tid >> 6;
    int orig = (tid < nb) ? bsum[tid] : 0;
    int v = orig;
#pragma unroll
    for (int off = 1; off < 64; off <<= 1) {
        int t = __shfl_up(v, off);
        if (lane >= off) v += t;
    }
    __shared__ int w0;
    if (lane == 63 && wv == 0) w0 = v;
    __syncthreads();
    if (wv == 1) v += w0;
    if (tid < nb) boff[tid] = v - orig;  // exclusive
}

__global__ __launch_bounds__(256) void k_scanC(const int* __restrict__ indeg,
                                               int* __restrict__ part,
                                               const int* __restrict__ boff,
                                               int* __restrict__ cursor, int n) {
    int idx = blockIdx.x * 256 + threadIdx.x;
    if (idx >= n) return;
    int pd = (indeg[idx] + 7) & ~7;
    int incl = part[idx] + boff[blockIdx.x];
    int excl = incl - pd;
    part[idx] = excl;      // part aliases rowstart
    cursor[idx] = excl;
    if (idx == n - 1) part[n] = incl;
}

__global__ void k_fill(const int* __restrict__ src, const int* __restrict__ dst,
                       const float* __restrict__ dis, int* __restrict__ cursor,
                       int2* __restrict__ pack, int E) {
    int e = blockIdx.x * blockDim.x + threadIdx.x;
    if (e >= E) return;
    int s = src[e], d = dst[e];
    int pos = atomicAdd(&cursor[d], 1);
    int2 v;
    v.x = s;
    v.y = __float_as_int(-dis[s] * dis[d]);
    pack[pos] = v;
}

// weight packing: all f32
__global__ void k_pack(const float* __restrict__ Wh, const float* __restrict__ Wx,
                       float4* __restrict__ Wh4, float2* __restrict__ Wh2,
                       float4* __restrict__ Wx4, float2* __restrict__ Wx2) {
    int idx = blockIdx.x * blockDim.x + threadIdx.x;
    if (idx < HID * HID) {
        int j = idx >> 6, f = idx & 63;
        float4 v4;
        v4.x = Wh[((0 * 2 + 0) * HID + j) * HID + f];
        v4.y = Wh[((0 * 2 + 1) * HID + j) * HID + f];
        v4.z = Wh[((1 * 2 + 0) * HID + j) * HID + f];
        v4.w = Wh[((1 * 2 + 1) * HID + j) * HID + f];
        Wh4[idx] = v4;
        float2 v2;
        v2.x = Wh[((2 * 2 + 0) * HID + j) * HID + f];
        v2.y = Wh[((2 * 2 + 1) * HID + j) * HID + f];
        Wh2[idx] = v2;
    } else if (idx < HID * HID + INF * HID) {
        int k = idx - HID * HID;
        int i = k >> 6, f = k & 63;
        float4 v4;
        v4.x = Wx[((0 * 2 + 0) * INF + i) * HID + f];
        v4.y = Wx[((0 * 2 + 1) * INF + i) * HID + f];
        v4.z = Wx[((1 * 2 + 0) * INF + i) * HID + f];
        v4.w = Wx[((1 * 2 + 1) * INF + i) * HID + f];
        Wx4[k] = v4;
        float2 v2;
        v2.x = Wx[((2 * 2 + 0) * INF + i) * HID + f];
        v2.y = Wx[((2 * 2 + 1) * INF + i) * HID + f];
        Wx2[k] = v2;
    }
}

__global__ void k_hzero(float* __restrict__ h, __half* __restrict__ h16, int nel) {
    int i = blockIdx.x * blockDim.x + threadIdx.x;
    if (i < nel) { h[i] = 0.0f; h16[i] = __float2half(0.0f); }
}

__global__ void k_xin0(const float* __restrict__ Xt, float* __restrict__ xin,
                       __half* __restrict__ xin16, int n) {
    int i = blockIdx.x * blockDim.x + threadIdx.x;
    if (i >= n) return;
    const float* xt = Xt + (size_t)i * INF;
    float* xo = xin + (size_t)i * XPAD;
    __half* xh = xin16 + (size_t)i * XPAD;
#pragma unroll
    for (int k = 0; k < INF; ++k) { float v = xt[k]; xo[k] = v; xh[k] = __float2half(v); }
#pragma unroll
    for (int k = INF; k < XPAD; ++k) { xo[k] = 0.0f; xh[k] = __float2half(0.0f); }
}

// ---------------- fused per-timestep kernels ----------------
// 512 threads = 8 waves x NPW(4) nodes = 32 nodes/block; NN/32 = 625 blocks exactly.
// __syncthreads() between gather and dense aligns the 8 waves' identical weight
// streams so L1 serves 7 of 8 (cuts L2 weight traffic ~8x).

__global__ __launch_bounds__(512) void k_gz(
    const int* __restrict__ rowstart, const int2* __restrict__ pack,
    const float* __restrict__ xin, const __half* __restrict__ xin16,
    const __half* __restrict__ h16,
    const float4* __restrict__ Wx4, const float* __restrict__ bx,
    const float4* __restrict__ Wh4, const float* __restrict__ bh,
    float* __restrict__ t1x, __half* __restrict__ Zb16,
    __half* __restrict__ hr16, int n) {
    int wid = __builtin_amdgcn_readfirstlane(
        (int)((blockIdx.x * blockDim.x + threadIdx.x) >> 6));
    int wbase = wid * NPW;
    int lane = threadIdx.x & 63;
    int f16i = lane & 15, eo = lane >> 4;

    float thg[NPW], axv[NPW], hv[NPW];
#pragma unroll
    for (int nn = 0; nn < NPW; ++nn) {
        int node = wbase + nn;
        hv[nn] = __half2float(h16[(size_t)node * HID + lane]);
        int s = rowstart[node], e = rowstart[node + 1];  // (e-s) % 8 == 0
        float a0 = 0, a1 = 0, a2 = 0, a3 = 0;
        float c0 = 0, c1 = 0;
        for (int p = s; p < e; p += 8) {
            int2 e0 = pack[p],     e1 = pack[p + 1], e2 = pack[p + 2], e3 = pack[p + 3];
            int2 e4 = pack[p + 4], e5 = pack[p + 5], e6 = pack[p + 6], e7 = pack[p + 7];
            float w0 = __int_as_float(e0.y), w1 = __int_as_float(e1.y);
            float w2 = __int_as_float(e2.y), w3 = __int_as_float(e3.y);
            float w4 = __int_as_float(e4.y), w5 = __int_as_float(e5.y);
            float w6 = __int_as_float(e6.y), w7 = __int_as_float(e7.y);
            a0 = fmaf(w0, __half2float(h16[(size_t)e0.x * HID + lane]), a0);
            a1 = fmaf(w1, __half2float(h16[(size_t)e1.x * HID + lane]), a1);
            a2 = fmaf(w2, __half2float(h16[(size_t)e2.x * HID + lane]), a2);
            a3 = fmaf(w3, __half2float(h16[(size_t)e3.x * HID + lane]), a3);
            a0 = fmaf(w4, __half2float(h16[(size_t)e4.x * HID + lane]), a0);
            a1 = fmaf(w5, __half2float(h16[(size_t)e5.x * HID + lane]), a1);
            a2 = fmaf(w6, __half2float(h16[(size_t)e6.x * HID + lane]), a2);
            a3 = fmaf(w7, __half2float(h16[(size_t)e7.x * HID + lane]), a3);
            int sx0 = (eo == 0) ? e0.x : (eo == 1) ? e2.x : (eo == 2) ? e4.x : e6.x;
            float wx0 = (eo == 0) ? w0 : (eo == 1) ? w2 : (eo == 2) ? w4 : w6;
            int sx1 = (eo == 0) ? e1.x : (eo == 1) ? e3.x : (eo == 2) ? e5.x : e7.x;
            float wx1 = (eo == 0) ? w1 : (eo == 1) ? w3 : (eo == 2) ? w5 : w7;
            c0 = fmaf(wx0, __half2float(xin16[(size_t)sx0 * XPAD + f16i]), c0);
            c1 = fmaf(wx1, __half2float(xin16[(size_t)sx1 * XPAD + f16i]), c1);
        }
        thg[nn] = (a0 + a1) + (a2 + a3);
        float cx = c0 + c1;
        cx += __shfl_down(cx, 32);
        cx += __shfl_down(cx, 16);
        axv[nn] = cx;  // valid lanes 0..15
    }
#pragma unroll
    for (int nn = 0; nn < NPW; ++nn)
        if (lane < 16) t1x[(size_t)(wbase + nn) * XPAD + lane] = axv[nn];

    __syncthreads();  // align 8 waves' weight streams for L1 sharing

    // dense Z/R
    float xrow = xin[(size_t)wbase * XPAD + lane];
    float b0z = bx[0 * HID + lane] + bh[0 * HID + lane];
    float b0r = bx[1 * HID + lane] + bh[1 * HID + lane];
    float az[NPW], ar[NPW];
#pragma unroll
    for (int nn = 0; nn < NPW; ++nn) { az[nn] = b0z; ar[nn] = b0r; }
#pragma unroll
    for (int i = 0; i < INF; ++i) {
        float4 w = Wx4[i * HID + lane];
#pragma unroll
        for (int nn = 0; nn < NPW; ++nn) {
            float xv = bcast(xrow, nn * XPAD + i);
            float tv = bcast(axv[nn], i);
            az[nn] = fmaf(xv, w.x, fmaf(tv, w.y, az[nn]));
            ar[nn] = fmaf(xv, w.z, fmaf(tv, w.w, ar[nn]));
        }
    }
#pragma unroll 8
    for (int j = 0; j < HID; ++j) {
        float4 w = Wh4[j * HID + lane];
#pragma unroll
        for (int nn = 0; nn < NPW; ++nn) {
            float hj = bcast(hv[nn], j);
            float tj = bcast(thg[nn], j);
            az[nn] = fmaf(hj, w.x, fmaf(tj, w.y, az[nn]));
            ar[nn] = fmaf(hj, w.z, fmaf(tj, w.w, ar[nn]));
        }
    }
#pragma unroll
    for (int nn = 0; nn < NPW; ++nn) {
        int node = wbase + nn;
        float Z = 1.0f / (1.0f + __expf(-az[nn]));
        float R = 1.0f / (1.0f + __expf(-ar[nn]));
        Zb16[(size_t)node * HID + lane] = __float2half(Z);
        hr16[(size_t)node * HID + lane] = __float2half(hv[nn] * R);
    }
}

__global__ __launch_bounds__(512) void k_gc(
    const int* __restrict__ rowstart, const int2* __restrict__ pack,
    const float* __restrict__ xin, const float* __restrict__ t1x,
    float* __restrict__ h, __half* __restrict__ h16,
    const __half* __restrict__ hr16,
    const float2* __restrict__ Wx2, const float* __restrict__ bx,
    const float2* __restrict__ Wh2, const float* __restrict__ bh,
    const __half* __restrict__ Zb16,
    const float* __restrict__ hw, const float* __restrict__ hb,
    float* __restrict__ out,
    const float* __restrict__ Xcur, const float* __restrict__ Xnxt,
    float* __restrict__ xin_w, __half* __restrict__ xin16_w,
    int last, int n) {
    int wid = __builtin_amdgcn_readfirstlane(
        (int)((blockIdx.x * blockDim.x + threadIdx.x) >> 6));
    int wbase = wid * NPW;
    int lane = threadIdx.x & 63;

    float thg[NPW], hrv[NPW];
#pragma unroll
    for (int nn = 0; nn < NPW; ++nn) {
        int node = wbase + nn;
        hrv[nn] = __half2float(hr16[(size_t)node * HID + lane]);
        int s = rowstart[node], e = rowstart[node + 1];
        float a0 = 0, a1 = 0, a2 = 0, a3 = 0;
        for (int p = s; p < e; p += 8) {
            int2 e0 = pack[p],     e1 = pack[p + 1], e2 = pack[p + 2], e3 = pack[p + 3];
            int2 e4 = pack[p + 4], e5 = pack[p + 5], e6 = pack[p + 6], e7 = pack[p + 7];
            a0 = fmaf(__int_as_float(e0.y), __half2float(hr16[(size_t)e0.x * HID + lane]), a0);
            a1 = fmaf(__int_as_float(e1.y), __half2float(hr16[(size_t)e1.x * HID + lane]), a1);
            a2 = fmaf(__int_as_float(e2.y), __half2float(hr16[(size_t)e2.x * HID + lane]), a2);
            a3 = fmaf(__int_as_float(e3.y), __half2float(hr16[(size_t)e3.x * HID + lane]), a3);
            a0 = fmaf(__int_as_float(e4.y), __half2float(hr16[(size_t)e4.x * HID + lane]), a0);
            a1 = fmaf(__int_as_float(e5.y), __half2float(hr16[(size_t)e5.x * HID + lane]), a1);
            a2 = fmaf(__int_as_float(e6.y), __half2float(hr16[(size_t)e6.x * HID + lane]), a2);
            a3 = fmaf(__int_as_float(e7.y), __half2float(hr16[(size_t)e7.x * HID + lane]), a3);
        }
        thg[nn] = (a0 + a1) + (a2 + a3);
    }

    __syncthreads();  // align weight streams

    float xrow = xin[(size_t)wbase * XPAD + lane];
    float trow = t1x[(size_t)wbase * XPAD + lane];
    float b0 = bx[2 * HID + lane] + bh[2 * HID + lane];
    float ah[NPW];
#pragma unroll
    for (int nn = 0; nn < NPW; ++nn) ah[nn] = b0;
#pragma unroll
    for (int i = 0; i < INF; ++i) {
        float2 w = Wx2[i * HID + lane];
#pragma unroll
        for (int nn = 0; nn < NPW; ++nn) {
            float xv = bcast(xrow, nn * XPAD + i);
            float tv = bcast(trow, nn * XPAD + i);
            ah[nn] = fmaf(xv, w.x, fmaf(tv, w.y, ah[nn]));
        }
    }
#pragma unroll 8
    for (int j = 0; j < HID; ++j) {
        float2 w = Wh2[j * HID + lane];
#pragma unroll
        for (int nn = 0; nn < NPW; ++nn) {
            float hj = bcast(hrv[nn], j);
            float tj = bcast(thg[nn], j);
            ah[nn] = fmaf(hj, w.x, fmaf(tj, w.y, ah[nn]));
        }
    }
#pragma unroll
    for (int nn = 0; nn < NPW; ++nn) {
        int node = wbase + nn;
        float Ht = tanh_safe(ah[nn]);
        float z = __half2float(Zb16[(size_t)node * HID + lane]);
        float hvv = h[(size_t)node * HID + lane];
        float hnew = z * hvv + (1.0f - z) * Ht;
        h[(size_t)node * HID + lane] = hnew;
        h16[(size_t)node * HID + lane] = __float2half(hnew);
        float u0, u1, u2;
        {
            float v0 = hnew * hw[lane * OUTF + 0];
            float v1 = hnew * hw[lane * OUTF + 1];
            float v2 = hnew * hw[lane * OUTF + 2];
            for (int off = 32; off; off >>= 1) {
                v0 += __shfl_down(v0, off);
                v1 += __shfl_down(v1, off);
                v2 += __shfl_down(v2, off);
            }
            u0 = bcast(v0, 0) + hb[0];
            u1 = bcast(v1, 0) + hb[1];
            u2 = bcast(v2, 0) + hb[2];
        }
        if (lane == 0) {
            float* o = out + (size_t)node * OUTF;
            o[0] = u0; o[1] = u1; o[2] = u2;
        }
        if (!last) {
            const float* x1r = Xnxt + (size_t)node * INF;
            const float* x0r = Xcur + (size_t)node * INF;
            float x1 = (lane < INF) ? x1r[lane] : 0.0f;
            float x0v = (lane >= 3 && lane < 7) ? x0r[lane] : 0.0f;
            float dt = bcast(x1, 6) - bcast(x0v, 6);
            float inv = 1.0f / dt;
            float c3 = bcast(x0v, 3), c4 = bcast(x0v, 4), c5 = bcast(x0v, 5);
            float val;
            if (lane < 3) val = x1;
            else if (lane < 6) val = (lane == 3) ? u0 : (lane == 4) ? u1 : u2;
            else if (lane < 8) val = x1;
            else if (lane < 11) {
                float uu = (lane == 8) ? u0 : (lane == 9) ? u1 : u2;
                float cc = (lane == 8) ? c3 : (lane == 9) ? c4 : c5;
                val = (uu - cc) * inv;
            } else val = 0.0f;
            if (lane < XPAD) {
                xin_w[(size_t)node * XPAD + lane] = val;
                xin16_w[(size_t)node * XPAD + lane] = __float2half(val);
            }
        }
    }
}

extern "C" void kernel_launch(void* const* d_in, const int* in_sizes, int n_in,
                              void* d_out, int out_size, void* d_ws, size_t ws_size,
                              hipStream_t stream) {
    const float* X_seq = (const float*)d_in[0];
    const int* edge = (const int*)d_in[1];
    const float* Wx = (const float*)d_in[2];
    const float* bx = (const float*)d_in[3];
    const float* Wh = (const float*)d_in[4];
    const float* bh = (const float*)d_in[5];
    const float* head_W = (const float*)d_in[6];
    const float* head_b = (const float*)d_in[7];
    float* out = (float*)d_out;

    const int* src = edge;
    const int* dst = edge + NE;

    // ---- workspace layout ----
    float* ws = (float*)d_ws;
    float4* Wh4g = (float4*)ws;                          // 4096 f4
    float4* Wx4g = (float4*)(ws + 16384);                // 704 f4
    float2* Wh2c = (float2*)(ws + 19200);                // 4096 f2
    float2* Wx2c = (float2*)(ws + 27392);                // 704 f2
    float* fbase = ws + 28800;
    float* dis  = fbase;                                 // N
    float* xin  = dis + NN;                              // N*16
    float* t1x  = xin + (size_t)NN * XPAD;               // N*16
    float* h    = t1x + (size_t)NN * XPAD;               // N*64
    int* degi     = (int*)(h + (size_t)NN * HID);        // N
    int* indeg    = degi + NN;                           // N
    int* rowstart = indeg + NN;                          // N+2
    int* cursor   = rowstart + NN + 2;                   // N
    int* bsum     = cursor + NN;                         // 128
    int* boff     = bsum + 128;                          // 128
    int2* pack    = (int2*)(boff + 128);                 // EPMAX int2
    __half* h16   = (__half*)(pack + EPMAX);             // N*64
    __half* hr16  = h16 + (size_t)NN * HID;              // N*64
    __half* Zb16  = hr16 + (size_t)NN * HID;             // N*64
    __half* xin16 = Zb16 + (size_t)NN * HID;             // N*16

    // ---- setup (once per call) ----
    hipMemsetAsync(degi, 0, 2 * NN * sizeof(int), stream);         // degi + indeg
    hipMemsetAsync(pack, 0, (size_t)EPMAX * sizeof(int2), stream); // zero pad slots
    k_cnt<<<(NE + 255) / 256, 256, 0, stream>>>(src, dst, degi, indeg, NE);
    k_dis<<<(NN + 255) / 256, 256, 0, stream>>>(degi, dis, NN);
    k_scanA<<<NB, 256, 0, stream>>>(indeg, rowstart, bsum, NN);
    k_scanB<<<1, 128, 0, stream>>>(bsum, boff, NB);
    k_scanC<<<NB, 256, 0, stream>>>(indeg, rowstart, boff, cursor, NN);
    k_fill<<<(NE + 255) / 256, 256, 0, stream>>>(src, dst, dis, cursor, pack, NE);
    k_pack<<<(HID * HID + INF * HID + 255) / 256, 256, 0, stream>>>(
        Wh, Wx, Wh4g, Wh2c, Wx4g, Wx2c);
    k_hzero<<<(NN * HID + 255) / 256, 256, 0, stream>>>(h, h16, NN * HID);

    k_xin0<<<(NN + 255) / 256, 256, 0, stream>>>(X_seq, xin, xin16, NN);

    const int fused_grid = NN / (WPB * NPW);  // 625, exact

    for (int t = 0; t < TSTEPS; ++t) {
        k_gz<<<fused_grid, 512, 0, stream>>>(rowstart, pack, xin, xin16, h16,
                                             Wx4g, bx, Wh4g, bh,
                                             t1x, Zb16, hr16, NN);

        const float* Xcur = X_seq + (size_t)t * NN * INF;
        const float* Xnxt = (t + 1 < TSTEPS) ? X_seq + (size_t)(t + 1) * NN * INF : X_seq;
        k_gc<<<fused_grid, 512, 0, stream>>>(rowstart, pack, xin, t1x, h, h16, hr16,
                                             Wx2c, bx, Wh2c, bh, Zb16,
                                             head_W, head_b,
                                             out + (size_t)t * NN * OUTF,
                                             Xcur, Xnxt, xin, xin16,
                                             (t + 1 == TSTEPS) ? 1 : 0, NN);
    }
}

// Round 13
// 437.374 us; speedup vs baseline: 1.1138x; 1.1138x over previous
//
#include <hip/hip_runtime.h>
#include <hip/hip_fp16.h>
#include <math.h>

#define TSTEPS 6
#define NN 20000
#define NE 320000
#define INF 11
#define XPAD 16
#define HID 64
#define OUTF 3
#define NPW 4                     // nodes per wave in fused kernels
#define EPMAX (NE + 7 * NN)       // CSR slots after pad-to-8
#define NB ((NN + 255) / 256)     // scan blocks = 79

__device__ __forceinline__ float bcast(float v, int l) {
    return __uint_as_float(__builtin_amdgcn_readlane(__float_as_uint(v), l));
}

__device__ __forceinline__ float tanh_safe(float a) {
    float e2 = __expf(-2.0f * fabsf(a));
    float t = (1.0f - e2) / (1.0f + e2);
    return copysignf(t, a);
}

// ---------------- setup kernels (once per call) ----------------

__global__ void k_cnt(const int* __restrict__ src, const int* __restrict__ dst,
                      int* __restrict__ degi, int* __restrict__ indeg, int E) {
    int e = blockIdx.x * blockDim.x + threadIdx.x;
    if (e >= E) return;
    atomicAdd(&degi[src[e]], 1);
    atomicAdd(&indeg[dst[e]], 1);
}

__global__ void k_dis(const int* __restrict__ degi, float* __restrict__ dis, int n) {
    int i = blockIdx.x * blockDim.x + threadIdx.x;
    if (i < n) {
        float d = (float)degi[i];
        dis[i] = d > 0.0f ? rsqrtf(fmaxf(d, 1.0f)) : 0.0f;
    }
}

// scanA: per-block inclusive scan of padded indeg into part, block totals to bsum
__global__ __launch_bounds__(256) void k_scanA(const int* __restrict__ indeg,
                                               int* __restrict__ part,
                                               int* __restrict__ bsum, int n) {
    int idx = blockIdx.x * 256 + threadIdx.x;
    int lane = threadIdx.x & 63, wv = threadIdx.x >> 6;
    int v = (idx < n) ? ((indeg[idx] + 7) & ~7) : 0;
#pragma unroll
    for (int off = 1; off < 64; off <<= 1) {
        int t = __shfl_up(v, off);
        if (lane >= off) v += t;
    }
    __shared__ int wsum[4];
    if (lane == 63) wsum[wv] = v;
    __syncthreads();
    int add = 0;
    for (int w = 0; w < wv; ++w) add += wsum[w];
    v += add;
    if (idx < n) part[idx] = v;
    if (threadIdx.x == 255) bsum[blockIdx.x] = v;
}

__global__ __launch_bounds__(128) void k_scanB(const int* __restrict__ bsum,
                                               int* __restrict__ boff, int nb) {
    int tid = threadIdx.x;
    int lane = tid & 63, wv = tid >> 6;
    int orig = (tid < nb) ? bsum[tid] : 0;
    int v = orig;
#pragma unroll
    for (int off = 1; off < 64; off <<= 1) {
        int t = __shfl_up(v, off);
        if (lane >= off) v += t;
    }
    __shared__ int w0;
    if (lane == 63 && wv == 0) w0 = v;
    __syncthreads();
    if (wv == 1) v += w0;
    if (tid < nb) boff[tid] = v - orig;  // exclusive
}

__global__ __launch_bounds__(256) void k_scanC(const int* __restrict__ indeg,
                                               int* __restrict__ part,
                                               const int* __restrict__ boff,
                                               int* __restrict__ cursor, int n) {
    int idx = blockIdx.x * 256 + threadIdx.x;
    if (idx >= n) return;
    int pd = (indeg[idx] + 7) & ~7;
    int incl = part[idx] + boff[blockIdx.x];
    int excl = incl - pd;
    part[idx] = excl;      // part aliases rowstart
    cursor[idx] = excl;
    if (idx == n - 1) part[n] = incl;
}

__global__ void k_fill(const int* __restrict__ src, const int* __restrict__ dst,
                       const float* __restrict__ dis, int* __restrict__ cursor,
                       int2* __restrict__ pack, int E) {
    int e = blockIdx.x * blockDim.x + threadIdx.x;
    if (e >= E) return;
    int s = src[e], d = dst[e];
    int pos = atomicAdd(&cursor[d], 1);
    int2 v;
    v.x = s;
    v.y = __float_as_int(-dis[s] * dis[d]);
    pack[pos] = v;
}

// weight packing: all f32
__global__ void k_pack(const float* __restrict__ Wh, const float* __restrict__ Wx,
                       float4* __restrict__ Wh4, float2* __restrict__ Wh2,
                       float4* __restrict__ Wx4, float2* __restrict__ Wx2) {
    int idx = blockIdx.x * blockDim.x + threadIdx.x;
    if (idx < HID * HID) {
        int j = idx >> 6, f = idx & 63;
        float4 v4;
        v4.x = Wh[((0 * 2 + 0) * HID + j) * HID + f];
        v4.y = Wh[((0 * 2 + 1) * HID + j) * HID + f];
        v4.z = Wh[((1 * 2 + 0) * HID + j) * HID + f];
        v4.w = Wh[((1 * 2 + 1) * HID + j) * HID + f];
        Wh4[idx] = v4;
        float2 v2;
        v2.x = Wh[((2 * 2 + 0) * HID + j) * HID + f];
        v2.y = Wh[((2 * 2 + 1) * HID + j) * HID + f];
        Wh2[idx] = v2;
    } else if (idx < HID * HID + INF * HID) {
        int k = idx - HID * HID;
        int i = k >> 6, f = k & 63;
        float4 v4;
        v4.x = Wx[((0 * 2 + 0) * INF + i) * HID + f];
        v4.y = Wx[((0 * 2 + 1) * INF + i) * HID + f];
        v4.z = Wx[((1 * 2 + 0) * INF + i) * HID + f];
        v4.w = Wx[((1 * 2 + 1) * INF + i) * HID + f];
        Wx4[k] = v4;
        float2 v2;
        v2.x = Wx[((2 * 2 + 0) * INF + i) * HID + f];
        v2.y = Wx[((2 * 2 + 1) * INF + i) * HID + f];
        Wx2[k] = v2;
    }
}

__global__ void k_hzero(float* __restrict__ h, __half* __restrict__ h16, int nel) {
    int i = blockIdx.x * blockDim.x + threadIdx.x;
    if (i < nel) { h[i] = 0.0f; h16[i] = __float2half(0.0f); }
}

__global__ void k_xin0(const float* __restrict__ Xt, float* __restrict__ xin,
                       __half* __restrict__ xin16, int n) {
    int i = blockIdx.x * blockDim.x + threadIdx.x;
    if (i >= n) return;
    const float* xt = Xt + (size_t)i * INF;
    float* xo = xin + (size_t)i * XPAD;
    __half* xh = xin16 + (size_t)i * XPAD;
#pragma unroll
    for (int k = 0; k < INF; ++k) { float v = xt[k]; xo[k] = v; xh[k] = __float2half(v); }
#pragma unroll
    for (int k = INF; k < XPAD; ++k) { xo[k] = 0.0f; xh[k] = __float2half(0.0f); }
}

// ---------------- fused per-timestep kernels ----------------

// gz: interleaved 4-node {h-gather + x-gather} + Z/R dense. No LDS.
// The 4 nodes' edge loops advance together: one round issues up to 32 h-loads
// before the waitcnt, cutting sequential latency rounds ~Sum(deg)/8 -> max(deg)/8.
__global__ __launch_bounds__(256) void k_gz(
    const int* __restrict__ rowstart, const int2* __restrict__ pack,
    const float* __restrict__ xin, const __half* __restrict__ xin16,
    const __half* __restrict__ h16,
    const float4* __restrict__ Wx4, const float* __restrict__ bx,
    const float4* __restrict__ Wh4, const float* __restrict__ bh,
    float* __restrict__ t1x, __half* __restrict__ Zb16,
    __half* __restrict__ hr16, int n) {
    int wid = __builtin_amdgcn_readfirstlane(
        (int)((blockIdx.x * blockDim.x + threadIdx.x) >> 6));
    int wbase = wid * NPW;
    int lane = threadIdx.x & 63;
    int f16i = lane & 15, eo = lane >> 4;
    if (wbase >= n) return;

    int ps[NPW], es[NPW];
    float A0[NPW], A1[NPW], C0[NPW], C1[NPW];
    float thg[NPW], axv[NPW], hv[NPW];
#pragma unroll
    for (int nn = 0; nn < NPW; ++nn) {
        int node = wbase + nn;
        ps[nn] = rowstart[node];
        es[nn] = rowstart[node + 1];    // (es-ps) % 8 == 0 (CSR padded)
        hv[nn] = __half2float(h16[(size_t)node * HID + lane]);
        A0[nn] = 0.0f; A1[nn] = 0.0f; C0[nn] = 0.0f; C1[nn] = 0.0f;
    }
    while ((ps[0] < es[0]) | (ps[1] < es[1]) | (ps[2] < es[2]) | (ps[3] < es[3])) {
#pragma unroll
        for (int nn = 0; nn < NPW; ++nn) {
            bool act = ps[nn] < es[nn];
            int q = act ? ps[nn] : 0;       // inactive: reload batch 0 with m=0
            float m = act ? 1.0f : 0.0f;
            int2 q0 = pack[q],     q1 = pack[q + 1], q2 = pack[q + 2], q3 = pack[q + 3];
            int2 q4 = pack[q + 4], q5 = pack[q + 5], q6 = pack[q + 6], q7 = pack[q + 7];
            float w0 = __int_as_float(q0.y) * m, w1 = __int_as_float(q1.y) * m;
            float w2 = __int_as_float(q2.y) * m, w3 = __int_as_float(q3.y) * m;
            float w4 = __int_as_float(q4.y) * m, w5 = __int_as_float(q5.y) * m;
            float w6 = __int_as_float(q6.y) * m, w7 = __int_as_float(q7.y) * m;
            A0[nn] = fmaf(w0, __half2float(h16[(size_t)q0.x * HID + lane]), A0[nn]);
            A1[nn] = fmaf(w1, __half2float(h16[(size_t)q1.x * HID + lane]), A1[nn]);
            A0[nn] = fmaf(w2, __half2float(h16[(size_t)q2.x * HID + lane]), A0[nn]);
            A1[nn] = fmaf(w3, __half2float(h16[(size_t)q3.x * HID + lane]), A1[nn]);
            A0[nn] = fmaf(w4, __half2float(h16[(size_t)q4.x * HID + lane]), A0[nn]);
            A1[nn] = fmaf(w5, __half2float(h16[(size_t)q5.x * HID + lane]), A1[nn]);
            A0[nn] = fmaf(w6, __half2float(h16[(size_t)q6.x * HID + lane]), A0[nn]);
            A1[nn] = fmaf(w7, __half2float(h16[(size_t)q7.x * HID + lane]), A1[nn]);
            // x-gather: lane-group eo handles edges 2*eo, 2*eo+1 (direct loads)
            int2 x0 = pack[q + 2 * eo], x1 = pack[q + 2 * eo + 1];
            C0[nn] = fmaf(__int_as_float(x0.y) * m,
                          __half2float(xin16[(size_t)x0.x * XPAD + f16i]), C0[nn]);
            C1[nn] = fmaf(__int_as_float(x1.y) * m,
                          __half2float(xin16[(size_t)x1.x * XPAD + f16i]), C1[nn]);
            ps[nn] += 8;
        }
    }
#pragma unroll
    for (int nn = 0; nn < NPW; ++nn) {
        thg[nn] = A0[nn] + A1[nn];
        float cx = C0[nn] + C1[nn];
        cx += __shfl_down(cx, 32);
        cx += __shfl_down(cx, 16);
        axv[nn] = cx;  // valid lanes 0..15
    }
#pragma unroll
    for (int nn = 0; nn < NPW; ++nn)
        if (lane < 16) t1x[(size_t)(wbase + nn) * XPAD + lane] = axv[nn];

    // dense Z/R
    float xrow = xin[(size_t)wbase * XPAD + lane];
    float b0z = bx[0 * HID + lane] + bh[0 * HID + lane];
    float b0r = bx[1 * HID + lane] + bh[1 * HID + lane];
    float az[NPW], ar[NPW];
#pragma unroll
    for (int nn = 0; nn < NPW; ++nn) { az[nn] = b0z; ar[nn] = b0r; }
#pragma unroll
    for (int i = 0; i < INF; ++i) {
        float4 w = Wx4[i * HID + lane];
#pragma unroll
        for (int nn = 0; nn < NPW; ++nn) {
            float xv = bcast(xrow, nn * XPAD + i);
            float tv = bcast(axv[nn], i);
            az[nn] = fmaf(xv, w.x, fmaf(tv, w.y, az[nn]));
            ar[nn] = fmaf(xv, w.z, fmaf(tv, w.w, ar[nn]));
        }
    }
#pragma unroll 8
    for (int j = 0; j < HID; ++j) {
        float4 w = Wh4[j * HID + lane];
#pragma unroll
        for (int nn = 0; nn < NPW; ++nn) {
            float hj = bcast(hv[nn], j);
            float tj = bcast(thg[nn], j);
            az[nn] = fmaf(hj, w.x, fmaf(tj, w.y, az[nn]));
            ar[nn] = fmaf(hj, w.z, fmaf(tj, w.w, ar[nn]));
        }
    }
#pragma unroll
    for (int nn = 0; nn < NPW; ++nn) {
        int node = wbase + nn;
        float Z = 1.0f / (1.0f + __expf(-az[nn]));
        float R = 1.0f / (1.0f + __expf(-ar[nn]));
        Zb16[(size_t)node * HID + lane] = __float2half(Z);
        hr16[(size_t)node * HID + lane] = __float2half(hv[nn] * R);
    }
}

// gc: interleaved 4-node hr-gather + candidate + blend + head + next xin. No LDS.
__global__ __launch_bounds__(256) void k_gc(
    const int* __restrict__ rowstart, const int2* __restrict__ pack,
    const float* __restrict__ xin, const float* __restrict__ t1x,
    float* __restrict__ h, __half* __restrict__ h16,
    const __half* __restrict__ hr16,
    const float2* __restrict__ Wx2, const float* __restrict__ bx,
    const float2* __restrict__ Wh2, const float* __restrict__ bh,
    const __half* __restrict__ Zb16,
    const float* __restrict__ hw, const float* __restrict__ hb,
    float* __restrict__ out,
    const float* __restrict__ Xcur, const float* __restrict__ Xnxt,
    float* __restrict__ xin_w, __half* __restrict__ xin16_w,
    int last, int n) {
    int wid = __builtin_amdgcn_readfirstlane(
        (int)((blockIdx.x * blockDim.x + threadIdx.x) >> 6));
    int wbase = wid * NPW;
    int lane = threadIdx.x & 63;
    if (wbase >= n) return;

    int ps[NPW], es[NPW];
    float A0[NPW], A1[NPW];
    float thg[NPW], hrv[NPW];
#pragma unroll
    for (int nn = 0; nn < NPW; ++nn) {
        int node = wbase + nn;
        ps[nn] = rowstart[node];
        es[nn] = rowstart[node + 1];
        hrv[nn] = __half2float(hr16[(size_t)node * HID + lane]);
        A0[nn] = 0.0f; A1[nn] = 0.0f;
    }
    while ((ps[0] < es[0]) | (ps[1] < es[1]) | (ps[2] < es[2]) | (ps[3] < es[3])) {
#pragma unroll
        for (int nn = 0; nn < NPW; ++nn) {
            bool act = ps[nn] < es[nn];
            int q = act ? ps[nn] : 0;
            float m = act ? 1.0f : 0.0f;
            int2 q0 = pack[q],     q1 = pack[q + 1], q2 = pack[q + 2], q3 = pack[q + 3];
            int2 q4 = pack[q + 4], q5 = pack[q + 5], q6 = pack[q + 6], q7 = pack[q + 7];
            A0[nn] = fmaf(__int_as_float(q0.y) * m,
                          __half2float(hr16[(size_t)q0.x * HID + lane]), A0[nn]);
            A1[nn] = fmaf(__int_as_float(q1.y) * m,
                          __half2float(hr16[(size_t)q1.x * HID + lane]), A1[nn]);
            A0[nn] = fmaf(__int_as_float(q2.y) * m,
                          __half2float(hr16[(size_t)q2.x * HID + lane]), A0[nn]);
            A1[nn] = fmaf(__int_as_float(q3.y) * m,
                          __half2float(hr16[(size_t)q3.x * HID + lane]), A1[nn]);
            A0[nn] = fmaf(__int_as_float(q4.y) * m,
                          __half2float(hr16[(size_t)q4.x * HID + lane]), A0[nn]);
            A1[nn] = fmaf(__int_as_float(q5.y) * m,
                          __half2float(hr16[(size_t)q5.x * HID + lane]), A1[nn]);
            A0[nn] = fmaf(__int_as_float(q6.y) * m,
                          __half2float(hr16[(size_t)q6.x * HID + lane]), A0[nn]);
            A1[nn] = fmaf(__int_as_float(q7.y) * m,
                          __half2float(hr16[(size_t)q7.x * HID + lane]), A1[nn]);
            ps[nn] += 8;
        }
    }
#pragma unroll
    for (int nn = 0; nn < NPW; ++nn) thg[nn] = A0[nn] + A1[nn];

    float xrow = xin[(size_t)wbase * XPAD + lane];
    float trow = t1x[(size_t)wbase * XPAD + lane];
    float b0 = bx[2 * HID + lane] + bh[2 * HID + lane];
    float ah[NPW];
#pragma unroll
    for (int nn = 0; nn < NPW; ++nn) ah[nn] = b0;
#pragma unroll
    for (int i = 0; i < INF; ++i) {
        float2 w = Wx2[i * HID + lane];
#pragma unroll
        for (int nn = 0; nn < NPW; ++nn) {
            float xv = bcast(xrow, nn * XPAD + i);
            float tv = bcast(trow, nn * XPAD + i);
            ah[nn] = fmaf(xv, w.x, fmaf(tv, w.y, ah[nn]));
        }
    }
#pragma unroll 8
    for (int j = 0; j < HID; ++j) {
        float2 w = Wh2[j * HID + lane];
#pragma unroll
        for (int nn = 0; nn < NPW; ++nn) {
            float hj = bcast(hrv[nn], j);
            float tj = bcast(thg[nn], j);
            ah[nn] = fmaf(hj, w.x, fmaf(tj, w.y, ah[nn]));
        }
    }
#pragma unroll
    for (int nn = 0; nn < NPW; ++nn) {
        int node = wbase + nn;
        float Ht = tanh_safe(ah[nn]);
        float z = __half2float(Zb16[(size_t)node * HID + lane]);
        float hvv = h[(size_t)node * HID + lane];
        float hnew = z * hvv + (1.0f - z) * Ht;
        h[(size_t)node * HID + lane] = hnew;
        h16[(size_t)node * HID + lane] = __float2half(hnew);
        float u0, u1, u2;
        {
            float v0 = hnew * hw[lane * OUTF + 0];
            float v1 = hnew * hw[lane * OUTF + 1];
            float v2 = hnew * hw[lane * OUTF + 2];
            for (int off = 32; off; off >>= 1) {
                v0 += __shfl_down(v0, off);
                v1 += __shfl_down(v1, off);
                v2 += __shfl_down(v2, off);
            }
            u0 = bcast(v0, 0) + hb[0];
            u1 = bcast(v1, 0) + hb[1];
            u2 = bcast(v2, 0) + hb[2];
        }
        if (lane == 0) {
            float* o = out + (size_t)node * OUTF;
            o[0] = u0; o[1] = u1; o[2] = u2;
        }
        if (!last) {
            const float* x1r = Xnxt + (size_t)node * INF;
            const float* x0r = Xcur + (size_t)node * INF;
            float x1 = (lane < INF) ? x1r[lane] : 0.0f;
            float x0v = (lane >= 3 && lane < 7) ? x0r[lane] : 0.0f;
            float dt = bcast(x1, 6) - bcast(x0v, 6);
            float inv = 1.0f / dt;
            float c3 = bcast(x0v, 3), c4 = bcast(x0v, 4), c5 = bcast(x0v, 5);
            float val;
            if (lane < 3) val = x1;
            else if (lane < 6) val = (lane == 3) ? u0 : (lane == 4) ? u1 : u2;
            else if (lane < 8) val = x1;
            else if (lane < 11) {
                float uu = (lane == 8) ? u0 : (lane == 9) ? u1 : u2;
                float cc = (lane == 8) ? c3 : (lane == 9) ? c4 : c5;
                val = (uu - cc) * inv;
            } else val = 0.0f;
            if (lane < XPAD) {
                xin_w[(size_t)node * XPAD + lane] = val;
                xin16_w[(size_t)node * XPAD + lane] = __float2half(val);
            }
        }
    }
}

extern "C" void kernel_launch(void* const* d_in, const int* in_sizes, int n_in,
                              void* d_out, int out_size, void* d_ws, size_t ws_size,
                              hipStream_t stream) {
    const float* X_seq = (const float*)d_in[0];
    const int* edge = (const int*)d_in[1];
    const float* Wx = (const float*)d_in[2];
    const float* bx = (const float*)d_in[3];
    const float* Wh = (const float*)d_in[4];
    const float* bh = (const float*)d_in[5];
    const float* head_W = (const float*)d_in[6];
    const float* head_b = (const float*)d_in[7];
    float* out = (float*)d_out;

    const int* src = edge;
    const int* dst = edge + NE;

    // ---- workspace layout ----
    float* ws = (float*)d_ws;
    float4* Wh4g = (float4*)ws;                          // 4096 f4
    float4* Wx4g = (float4*)(ws + 16384);                // 704 f4
    float2* Wh2c = (float2*)(ws + 19200);                // 4096 f2
    float2* Wx2c = (float2*)(ws + 27392);                // 704 f2
    float* fbase = ws + 28800;
    float* dis  = fbase;                                 // N
    float* xin  = dis + NN;                              // N*16
    float* t1x  = xin + (size_t)NN * XPAD;               // N*16
    float* h    = t1x + (size_t)NN * XPAD;               // N*64
    int* degi     = (int*)(h + (size_t)NN * HID);        // N
    int* indeg    = degi + NN;                           // N
    int* rowstart = indeg + NN;                          // N+2
    int* cursor   = rowstart + NN + 2;                   // N
    int* bsum     = cursor + NN;                         // 128
    int* boff     = bsum + 128;                          // 128
    int2* pack    = (int2*)(boff + 128);                 // EPMAX int2
    __half* h16   = (__half*)(pack + EPMAX);             // N*64
    __half* hr16  = h16 + (size_t)NN * HID;              // N*64
    __half* Zb16  = hr16 + (size_t)NN * HID;             // N*64
    __half* xin16 = Zb16 + (size_t)NN * HID;             // N*16

    // ---- setup (once per call) ----
    hipMemsetAsync(degi, 0, 2 * NN * sizeof(int), stream);         // degi + indeg
    hipMemsetAsync(pack, 0, (size_t)EPMAX * sizeof(int2), stream); // zero pad slots
    k_cnt<<<(NE + 255) / 256, 256, 0, stream>>>(src, dst, degi, indeg, NE);
    k_dis<<<(NN + 255) / 256, 256, 0, stream>>>(degi, dis, NN);
    k_scanA<<<NB, 256, 0, stream>>>(indeg, rowstart, bsum, NN);
    k_scanB<<<1, 128, 0, stream>>>(bsum, boff, NB);
    k_scanC<<<NB, 256, 0, stream>>>(indeg, rowstart, boff, cursor, NN);
    k_fill<<<(NE + 255) / 256, 256, 0, stream>>>(src, dst, dis, cursor, pack, NE);
    k_pack<<<(HID * HID + INF * HID + 255) / 256, 256, 0, stream>>>(
        Wh, Wx, Wh4g, Wh2c, Wx4g, Wx2c);
    k_hzero<<<(NN * HID + 255) / 256, 256, 0, stream>>>(h, h16, NN * HID);

    k_xin0<<<(NN + 255) / 256, 256, 0, stream>>>(X_seq, xin, xin16, NN);

    const int fused_grid = (NN + 4 * NPW - 1) / (4 * NPW);  // 1250

    for (int t = 0; t < TSTEPS; ++t) {
        k_gz<<<fused_grid, 256, 0, stream>>>(rowstart, pack, xin, xin16, h16,
                                             Wx4g, bx, Wh4g, bh,
                                             t1x, Zb16, hr16, NN);

        const float* Xcur = X_seq + (size_t)t * NN * INF;
        const float* Xnxt = (t + 1 < TSTEPS) ? X_seq + (size_t)(t + 1) * NN * INF : X_seq;
        k_gc<<<fused_grid, 256, 0, stream>>>(rowstart, pack, xin, t1x, h, h16, hr16,
                                             Wx2c, bx, Wh2c, bh, Zb16,
                                             head_W, head_b,
                                             out + (size_t)t * NN * OUTF,
                                             Xcur, Xnxt, xin, xin16,
                                             (t + 1 == TSTEPS) ? 1 : 0, NN);
    }
}

// Round 15
// 434.886 us; speedup vs baseline: 1.1202x; 1.0057x over previous
//
#include <hip/hip_runtime.h>
#include <hip/hip_fp16.h>
#include <math.h>

#define TSTEPS 6
#define NN 20000
#define NE 320000
#define INF 11
#define XPAD 16
#define HID 64
#define OUTF 3
#define NPW 4                     // nodes per wave in fused kernels
#define EPMAX (NE + 7 * NN)       // CSR slots after pad-to-8
#define NB ((NN + 255) / 256)     // scan blocks = 79

__device__ __forceinline__ float bcast(float v, int l) {
    return __uint_as_float(__builtin_amdgcn_readlane(__float_as_uint(v), l));
}

__device__ __forceinline__ float tanh_safe(float a) {
    float e2 = __expf(-2.0f * fabsf(a));
    float t = (1.0f - e2) / (1.0f + e2);
    return copysignf(t, a);
}

// ---------------- setup kernels (once per call) ----------------

__global__ void k_cnt(const int* __restrict__ src, const int* __restrict__ dst,
                      int* __restrict__ degi, int* __restrict__ indeg, int E) {
    int e = blockIdx.x * blockDim.x + threadIdx.x;
    if (e >= E) return;
    atomicAdd(&degi[src[e]], 1);
    atomicAdd(&indeg[dst[e]], 1);
}

// scanA: per-block inclusive scan of padded indeg into part, block totals to bsum
__global__ __launch_bounds__(256) void k_scanA(const int* __restrict__ indeg,
                                               int* __restrict__ part,
                                               int* __restrict__ bsum, int n) {
    int idx = blockIdx.x * 256 + threadIdx.x;
    int lane = threadIdx.x & 63, wv = threadIdx.x >> 6;
    int v = (idx < n) ? ((indeg[idx] + 7) & ~7) : 0;
#pragma unroll
    for (int off = 1; off < 64; off <<= 1) {
        int t = __shfl_up(v, off);
        if (lane >= off) v += t;
    }
    __shared__ int wsum[4];
    if (lane == 63) wsum[wv] = v;
    __syncthreads();
    int add = 0;
    for (int w = 0; w < wv; ++w) add += wsum[w];
    v += add;
    if (idx < n) part[idx] = v;
    if (threadIdx.x == 255) bsum[blockIdx.x] = v;
}

__global__ __launch_bounds__(128) void k_scanB(const int* __restrict__ bsum,
                                               int* __restrict__ boff, int nb) {
    int tid = threadIdx.x;
    int lane = tid & 63, wv = tid >> 6;
    int orig = (tid < nb) ? bsum[tid] : 0;
    int v = orig;
#pragma unroll
    for (int off = 1; off < 64; off <<= 1) {
        int t = __shfl_up(v, off);
        if (lane >= off) v += t;
    }
    __shared__ int w0;
    if (lane == 63 && wv == 0) w0 = v;
    __syncthreads();
    if (wv == 1) v += w0;
    if (tid < nb) boff[tid] = v - orig;  // exclusive
}

__global__ __launch_bounds__(256) void k_scanC(const int* __restrict__ indeg,
                                               int* __restrict__ part,
                                               const int* __restrict__ boff,
                                               int* __restrict__ cursor, int n) {
    int idx = blockIdx.x * 256 + threadIdx.x;
    if (idx >= n) return;
    int pd = (indeg[idx] + 7) & ~7;
    int incl = part[idx] + boff[blockIdx.x];
    int excl = incl - pd;
    part[idx] = excl;      // part aliases rowstart
    cursor[idx] = excl;
    if (idx == n - 1) part[n] = incl;
}

// fill CSR: packed {src, w} int2, bucketed by dst; norm computed inline from degi
__global__ void k_fill(const int* __restrict__ src, const int* __restrict__ dst,
                       const int* __restrict__ degi, int* __restrict__ cursor,
                       int2* __restrict__ pack, int E) {
    int e = blockIdx.x * blockDim.x + threadIdx.x;
    if (e >= E) return;
    int s = src[e], d = dst[e];
    float ds = (float)degi[s];
    float dd = (float)degi[d];
    float ns = ds > 0.0f ? rsqrtf(fmaxf(ds, 1.0f)) : 0.0f;
    float nd = dd > 0.0f ? rsqrtf(fmaxf(dd, 1.0f)) : 0.0f;
    int pos = atomicAdd(&cursor[d], 1);
    int2 v;
    v.x = s;
    v.y = __float_as_int(-ns * nd);
    pack[pos] = v;
}

// merged init: weight packing + h/h16 zero + t0 xin build (disjoint index ranges)
__global__ void k_init(const float* __restrict__ Wh, const float* __restrict__ Wx,
                       float4* __restrict__ Wh4, float2* __restrict__ Wh2,
                       float4* __restrict__ Wx4, float2* __restrict__ Wx2,
                       float* __restrict__ h, __half* __restrict__ h16,
                       const float* __restrict__ Xt, float* __restrict__ xin,
                       __half* __restrict__ xin16) {
    int idx = blockIdx.x * blockDim.x + threadIdx.x;
    // task 1: zero h / h16 (covers full grid, NN*HID)
    if (idx < NN * HID) { h[idx] = 0.0f; h16[idx] = __float2half(0.0f); }
    // task 2: weight packing (first 4800 threads)
    if (idx < HID * HID) {
        int j = idx >> 6, f = idx & 63;
        float4 v4;
        v4.x = Wh[((0 * 2 + 0) * HID + j) * HID + f];
        v4.y = Wh[((0 * 2 + 1) * HID + j) * HID + f];
        v4.z = Wh[((1 * 2 + 0) * HID + j) * HID + f];
        v4.w = Wh[((1 * 2 + 1) * HID + j) * HID + f];
        Wh4[idx] = v4;
        float2 v2;
        v2.x = Wh[((2 * 2 + 0) * HID + j) * HID + f];
        v2.y = Wh[((2 * 2 + 1) * HID + j) * HID + f];
        Wh2[idx] = v2;
    } else if (idx < HID * HID + INF * HID) {
        int k = idx - HID * HID;
        int i = k >> 6, f = k & 63;
        float4 v4;
        v4.x = Wx[((0 * 2 + 0) * INF + i) * HID + f];
        v4.y = Wx[((0 * 2 + 1) * INF + i) * HID + f];
        v4.z = Wx[((1 * 2 + 0) * INF + i) * HID + f];
        v4.w = Wx[((1 * 2 + 1) * INF + i) * HID + f];
        Wx4[k] = v4;
        float2 v2;
        v2.x = Wx[((2 * 2 + 0) * INF + i) * HID + f];
        v2.y = Wx[((2 * 2 + 1) * INF + i) * HID + f];
        Wx2[k] = v2;
    }
    // task 3: t=0 xin build (first NN threads)
    if (idx < NN) {
        const float* xt = Xt + (size_t)idx * INF;
        float* xo = xin + (size_t)idx * XPAD;
        __half* xh = xin16 + (size_t)idx * XPAD;
#pragma unroll
        for (int k = 0; k < INF; ++k) { float v = xt[k]; xo[k] = v; xh[k] = __float2half(v); }
#pragma unroll
        for (int k = INF; k < XPAD; ++k) { xo[k] = 0.0f; xh[k] = __float2half(0.0f); }
    }
}

// ---------------- fused per-timestep kernels (byte-identical to round 13) ----------------

// gz: interleaved 4-node {h-gather + x-gather} + Z/R dense. No LDS.
__global__ __launch_bounds__(256) void k_gz(
    const int* __restrict__ rowstart, const int2* __restrict__ pack,
    const float* __restrict__ xin, const __half* __restrict__ xin16,
    const __half* __restrict__ h16,
    const float4* __restrict__ Wx4, const float* __restrict__ bx,
    const float4* __restrict__ Wh4, const float* __restrict__ bh,
    float* __restrict__ t1x, __half* __restrict__ Zb16,
    __half* __restrict__ hr16, int n) {
    int wid = __builtin_amdgcn_readfirstlane(
        (int)((blockIdx.x * blockDim.x + threadIdx.x) >> 6));
    int wbase = wid * NPW;
    int lane = threadIdx.x & 63;
    int f16i = lane & 15, eo = lane >> 4;
    if (wbase >= n) return;

    int ps[NPW], es[NPW];
    float A0[NPW], A1[NPW], C0[NPW], C1[NPW];
    float thg[NPW], axv[NPW], hv[NPW];
#pragma unroll
    for (int nn = 0; nn < NPW; ++nn) {
        int node = wbase + nn;
        ps[nn] = rowstart[node];
        es[nn] = rowstart[node + 1];    // (es-ps) % 8 == 0 (CSR padded)
        hv[nn] = __half2float(h16[(size_t)node * HID + lane]);
        A0[nn] = 0.0f; A1[nn] = 0.0f; C0[nn] = 0.0f; C1[nn] = 0.0f;
    }
    while ((ps[0] < es[0]) | (ps[1] < es[1]) | (ps[2] < es[2]) | (ps[3] < es[3])) {
#pragma unroll
        for (int nn = 0; nn < NPW; ++nn) {
            bool act = ps[nn] < es[nn];
            int q = act ? ps[nn] : 0;       // inactive: reload batch 0 with m=0
            float m = act ? 1.0f : 0.0f;
            int2 q0 = pack[q],     q1 = pack[q + 1], q2 = pack[q + 2], q3 = pack[q + 3];
            int2 q4 = pack[q + 4], q5 = pack[q + 5], q6 = pack[q + 6], q7 = pack[q + 7];
            float w0 = __int_as_float(q0.y) * m, w1 = __int_as_float(q1.y) * m;
            float w2 = __int_as_float(q2.y) * m, w3 = __int_as_float(q3.y) * m;
            float w4 = __int_as_float(q4.y) * m, w5 = __int_as_float(q5.y) * m;
            float w6 = __int_as_float(q6.y) * m, w7 = __int_as_float(q7.y) * m;
            A0[nn] = fmaf(w0, __half2float(h16[(size_t)q0.x * HID + lane]), A0[nn]);
            A1[nn] = fmaf(w1, __half2float(h16[(size_t)q1.x * HID + lane]), A1[nn]);
            A0[nn] = fmaf(w2, __half2float(h16[(size_t)q2.x * HID + lane]), A0[nn]);
            A1[nn] = fmaf(w3, __half2float(h16[(size_t)q3.x * HID + lane]), A1[nn]);
            A0[nn] = fmaf(w4, __half2float(h16[(size_t)q4.x * HID + lane]), A0[nn]);
            A1[nn] = fmaf(w5, __half2float(h16[(size_t)q5.x * HID + lane]), A1[nn]);
            A0[nn] = fmaf(w6, __half2float(h16[(size_t)q6.x * HID + lane]), A0[nn]);
            A1[nn] = fmaf(w7, __half2float(h16[(size_t)q7.x * HID + lane]), A1[nn]);
            // x-gather: lane-group eo handles edges 2*eo, 2*eo+1 (direct loads)
            int2 x0 = pack[q + 2 * eo], x1 = pack[q + 2 * eo + 1];
            C0[nn] = fmaf(__int_as_float(x0.y) * m,
                          __half2float(xin16[(size_t)x0.x * XPAD + f16i]), C0[nn]);
            C1[nn] = fmaf(__int_as_float(x1.y) * m,
                          __half2float(xin16[(size_t)x1.x * XPAD + f16i]), C1[nn]);
            ps[nn] += 8;
        }
    }
#pragma unroll
    for (int nn = 0; nn < NPW; ++nn) {
        thg[nn] = A0[nn] + A1[nn];
        float cx = C0[nn] + C1[nn];
        cx += __shfl_down(cx, 32);
        cx += __shfl_down(cx, 16);
        axv[nn] = cx;  // valid lanes 0..15
    }
#pragma unroll
    for (int nn = 0; nn < NPW; ++nn)
        if (lane < 16) t1x[(size_t)(wbase + nn) * XPAD + lane] = axv[nn];

    // dense Z/R
    float xrow = xin[(size_t)wbase * XPAD + lane];
    float b0z = bx[0 * HID + lane] + bh[0 * HID + lane];
    float b0r = bx[1 * HID + lane] + bh[1 * HID + lane];
    float az[NPW], ar[NPW];
#pragma unroll
    for (int nn = 0; nn < NPW; ++nn) { az[nn] = b0z; ar[nn] = b0r; }
#pragma unroll
    for (int i = 0; i < INF; ++i) {
        float4 w = Wx4[i * HID + lane];
#pragma unroll
        for (int nn = 0; nn < NPW; ++nn) {
            float xv = bcast(xrow, nn * XPAD + i);
            float tv = bcast(axv[nn], i);
            az[nn] = fmaf(xv, w.x, fmaf(tv, w.y, az[nn]));
            ar[nn] = fmaf(xv, w.z, fmaf(tv, w.w, ar[nn]));
        }
    }
#pragma unroll 8
    for (int j = 0; j < HID; ++j) {
        float4 w = Wh4[j * HID + lane];
#pragma unroll
        for (int nn = 0; nn < NPW; ++nn) {
            float hj = bcast(hv[nn], j);
            float tj = bcast(thg[nn], j);
            az[nn] = fmaf(hj, w.x, fmaf(tj, w.y, az[nn]));
            ar[nn] = fmaf(hj, w.z, fmaf(tj, w.w, ar[nn]));
        }
    }
#pragma unroll
    for (int nn = 0; nn < NPW; ++nn) {
        int node = wbase + nn;
        float Z = 1.0f / (1.0f + __expf(-az[nn]));
        float R = 1.0f / (1.0f + __expf(-ar[nn]));
        Zb16[(size_t)node * HID + lane] = __float2half(Z);
        hr16[(size_t)node * HID + lane] = __float2half(hv[nn] * R);
    }
}

// gc: interleaved 4-node hr-gather + candidate + blend + head + next xin. No LDS.
__global__ __launch_bounds__(256) void k_gc(
    const int* __restrict__ rowstart, const int2* __restrict__ pack,
    const float* __restrict__ xin, const float* __restrict__ t1x,
    float* __restrict__ h, __half* __restrict__ h16,
    const __half* __restrict__ hr16,
    const float2* __restrict__ Wx2, const float* __restrict__ bx,
    const float2* __restrict__ Wh2, const float* __restrict__ bh,
    const __half* __restrict__ Zb16,
    const float* __restrict__ hw, const float* __restrict__ hb,
    float* __restrict__ out,
    const float* __restrict__ Xcur, const float* __restrict__ Xnxt,
    float* __restrict__ xin_w, __half* __restrict__ xin16_w,
    int last, int n) {
    int wid = __builtin_amdgcn_readfirstlane(
        (int)((blockIdx.x * blockDim.x + threadIdx.x) >> 6));
    int wbase = wid * NPW;
    int lane = threadIdx.x & 63;
    if (wbase >= n) return;

    int ps[NPW], es[NPW];
    float A0[NPW], A1[NPW];
    float thg[NPW], hrv[NPW];
#pragma unroll
    for (int nn = 0; nn < NPW; ++nn) {
        int node = wbase + nn;
        ps[nn] = rowstart[node];
        es[nn] = rowstart[node + 1];
        hrv[nn] = __half2float(hr16[(size_t)node * HID + lane]);
        A0[nn] = 0.0f; A1[nn] = 0.0f;
    }
    while ((ps[0] < es[0]) | (ps[1] < es[1]) | (ps[2] < es[2]) | (ps[3] < es[3])) {
#pragma unroll
        for (int nn = 0; nn < NPW; ++nn) {
            bool act = ps[nn] < es[nn];
            int q = act ? ps[nn] : 0;
            float m = act ? 1.0f : 0.0f;
            int2 q0 = pack[q],     q1 = pack[q + 1], q2 = pack[q + 2], q3 = pack[q + 3];
            int2 q4 = pack[q + 4], q5 = pack[q + 5], q6 = pack[q + 6], q7 = pack[q + 7];
            A0[nn] = fmaf(__int_as_float(q0.y) * m,
                          __half2float(hr16[(size_t)q0.x * HID + lane]), A0[nn]);
            A1[nn] = fmaf(__int_as_float(q1.y) * m,
                          __half2float(hr16[(size_t)q1.x * HID + lane]), A1[nn]);
            A0[nn] = fmaf(__int_as_float(q2.y) * m,
                          __half2float(hr16[(size_t)q2.x * HID + lane]), A0[nn]);
            A1[nn] = fmaf(__int_as_float(q3.y) * m,
                          __half2float(hr16[(size_t)q3.x * HID + lane]), A1[nn]);
            A0[nn] = fmaf(__int_as_float(q4.y) * m,
                          __half2float(hr16[(size_t)q4.x * HID + lane]), A0[nn]);
            A1[nn] = fmaf(__int_as_float(q5.y) * m,
                          __half2float(hr16[(size_t)q5.x * HID + lane]), A1[nn]);
            A0[nn] = fmaf(__int_as_float(q6.y) * m,
                          __half2float(hr16[(size_t)q6.x * HID + lane]), A0[nn]);
            A1[nn] = fmaf(__int_as_float(q7.y) * m,
                          __half2float(hr16[(size_t)q7.x * HID + lane]), A1[nn]);
            ps[nn] += 8;
        }
    }
#pragma unroll
    for (int nn = 0; nn < NPW; ++nn) thg[nn] = A0[nn] + A1[nn];

    float xrow = xin[(size_t)wbase * XPAD + lane];
    float trow = t1x[(size_t)wbase * XPAD + lane];
    float b0 = bx[2 * HID + lane] + bh[2 * HID + lane];
    float ah[NPW];
#pragma unroll
    for (int nn = 0; nn < NPW; ++nn) ah[nn] = b0;
#pragma unroll
    for (int i = 0; i < INF; ++i) {
        float2 w = Wx2[i * HID + lane];
#pragma unroll
        for (int nn = 0; nn < NPW; ++nn) {
            float xv = bcast(xrow, nn * XPAD + i);
            float tv = bcast(trow, nn * XPAD + i);
            ah[nn] = fmaf(xv, w.x, fmaf(tv, w.y, ah[nn]));
        }
    }
#pragma unroll 8
    for (int j = 0; j < HID; ++j) {
        float2 w = Wh2[j * HID + lane];
#pragma unroll
        for (int nn = 0; nn < NPW; ++nn) {
            float hj = bcast(hrv[nn], j);
            float tj = bcast(thg[nn], j);
            ah[nn] = fmaf(hj, w.x, fmaf(tj, w.y, ah[nn]));
        }
    }
#pragma unroll
    for (int nn = 0; nn < NPW; ++nn) {
        int node = wbase + nn;
        float Ht = tanh_safe(ah[nn]);
        float z = __half2float(Zb16[(size_t)node * HID + lane]);
        float hvv = h[(size_t)node * HID + lane];
        float hnew = z * hvv + (1.0f - z) * Ht;
        h[(size_t)node * HID + lane] = hnew;
        h16[(size_t)node * HID + lane] = __float2half(hnew);
        float u0, u1, u2;
        {
            float v0 = hnew * hw[lane * OUTF + 0];
            float v1 = hnew * hw[lane * OUTF + 1];
            float v2 = hnew * hw[lane * OUTF + 2];
            for (int off = 32; off; off >>= 1) {
                v0 += __shfl_down(v0, off);
                v1 += __shfl_down(v1, off);
                v2 += __shfl_down(v2, off);
            }
            u0 = bcast(v0, 0) + hb[0];
            u1 = bcast(v1, 0) + hb[1];
            u2 = bcast(v2, 0) + hb[2];
        }
        if (lane == 0) {
            float* o = out + (size_t)node * OUTF;
            o[0] = u0; o[1] = u1; o[2] = u2;
        }
        if (!last) {
            const float* x1r = Xnxt + (size_t)node * INF;
            const float* x0r = Xcur + (size_t)node * INF;
            float x1 = (lane < INF) ? x1r[lane] : 0.0f;
            float x0v = (lane >= 3 && lane < 7) ? x0r[lane] : 0.0f;
            float dt = bcast(x1, 6) - bcast(x0v, 6);
            float inv = 1.0f / dt;
            float c3 = bcast(x0v, 3), c4 = bcast(x0v, 4), c5 = bcast(x0v, 5);
            float val;
            if (lane < 3) val = x1;
            else if (lane < 6) val = (lane == 3) ? u0 : (lane == 4) ? u1 : u2;
            else if (lane < 8) val = x1;
            else if (lane < 11) {
                float uu = (lane == 8) ? u0 : (lane == 9) ? u1 : u2;
                float cc = (lane == 8) ? c3 : (lane == 9) ? c4 : c5;
                val = (uu - cc) * inv;
            } else val = 0.0f;
            if (lane < XPAD) {
                xin_w[(size_t)node * XPAD + lane] = val;
                xin16_w[(size_t)node * XPAD + lane] = __float2half(val);
            }
        }
    }
}

extern "C" void kernel_launch(void* const* d_in, const int* in_sizes, int n_in,
                              void* d_out, int out_size, void* d_ws, size_t ws_size,
                              hipStream_t stream) {
    const float* X_seq = (const float*)d_in[0];
    const int* edge = (const int*)d_in[1];
    const float* Wx = (const float*)d_in[2];
    const float* bx = (const float*)d_in[3];
    const float* Wh = (const float*)d_in[4];
    const float* bh = (const float*)d_in[5];
    const float* head_W = (const float*)d_in[6];
    const float* head_b = (const float*)d_in[7];
    float* out = (float*)d_out;

    const int* src = edge;
    const int* dst = edge + NE;

    // ---- workspace layout ----
    float* ws = (float*)d_ws;
    float4* Wh4g = (float4*)ws;                          // 4096 f4
    float4* Wx4g = (float4*)(ws + 16384);                // 704 f4
    float2* Wh2c = (float2*)(ws + 19200);                // 4096 f2
    float2* Wx2c = (float2*)(ws + 27392);                // 704 f2
    float* fbase = ws + 28800;
    float* xin  = fbase;                                 // N*16
    float* t1x  = xin + (size_t)NN * XPAD;               // N*16
    float* h    = t1x + (size_t)NN * XPAD;               // N*64
    int* degi     = (int*)(h + (size_t)NN * HID);        // N
    int* indeg    = degi + NN;                           // N
    int* rowstart = indeg + NN;                          // N+2
    int* cursor   = rowstart + NN + 2;                   // N
    int* bsum     = cursor + NN;                         // 128
    int* boff     = bsum + 128;                          // 128
    int2* pack    = (int2*)(boff + 128);                 // EPMAX int2
    __half* h16   = (__half*)(pack + EPMAX);             // N*64
    __half* hr16  = h16 + (size_t)NN * HID;              // N*64
    __half* Zb16  = hr16 + (size_t)NN * HID;             // N*64
    __half* xin16 = Zb16 + (size_t)NN * HID;             // N*16

    // ---- setup (once per call): 2 memsets + 6 kernels ----
    hipMemsetAsync(degi, 0, 2 * NN * sizeof(int), stream);         // degi + indeg
    hipMemsetAsync(pack, 0, (size_t)EPMAX * sizeof(int2), stream); // zero pad slots
    k_cnt<<<(NE + 255) / 256, 256, 0, stream>>>(src, dst, degi, indeg, NE);
    k_scanA<<<NB, 256, 0, stream>>>(indeg, rowstart, bsum, NN);
    k_scanB<<<1, 128, 0, stream>>>(bsum, boff, NB);
    k_scanC<<<NB, 256, 0, stream>>>(indeg, rowstart, boff, cursor, NN);
    k_fill<<<(NE + 255) / 256, 256, 0, stream>>>(src, dst, degi, cursor, pack, NE);
    k_init<<<(NN * HID + 255) / 256, 256, 0, stream>>>(
        Wh, Wx, Wh4g, Wh2c, Wx4g, Wx2c, h, h16, X_seq, xin, xin16);

    const int fused_grid = (NN + 4 * NPW - 1) / (4 * NPW);  // 1250

    for (int t = 0; t < TSTEPS; ++t) {
        k_gz<<<fused_grid, 256, 0, stream>>>(rowstart, pack, xin, xin16, h16,
                                             Wx4g, bx, Wh4g, bh,
                                             t1x, Zb16, hr16, NN);

        const float* Xcur = X_seq + (size_t)t * NN * INF;
        const float* Xnxt = (t + 1 < TSTEPS) ? X_seq + (size_t)(t + 1) * NN * INF : X_seq;
        k_gc<<<fused_grid, 256, 0, stream>>>(rowstart, pack, xin, t1x, h, h16, hr16,
                                             Wx2c, bx, Wh2c, bh, Zb16,
                                             head_W, head_b,
                                             out + (size_t)t * NN * OUTF,
                                             Xcur, Xnxt, xin, xin16,
                                             (t + 1 == TSTEPS) ? 1 : 0, NN);
    }
}